// Round 6
// baseline (199.764 us; speedup 1.0000x reference)
//
#include <hip/hip_runtime.h>

#define T_TOK 8192
#define DIM   512
#define HID   1024
#define OUTD  512
#define NE    8

typedef __attribute__((ext_vector_type(8))) short short8v;   // 8 bf16 (4 VGPRs)
typedef __attribute__((ext_vector_type(4))) float f32x4;

__device__ __forceinline__ unsigned short f2bf(float f) {
  unsigned int u = __builtin_bit_cast(unsigned int, f);
  u += 0x7fffu + ((u >> 16) & 1u);            // RNE, finite inputs
  return (unsigned short)(u >> 16);
}

__device__ __forceinline__ void gload_lds16(const void* g, void* l) {
  __builtin_amdgcn_global_load_lds(
      (__attribute__((address_space(1))) void*)g,
      (__attribute__((address_space(3))) void*)l, 16, 0, 0);
}

__device__ __forceinline__ float gelu_f(float v) {
  const float c0 = 0.7978845608028654f;       // sqrt(2/pi), jax approximate=True
  float u = c0 * (v + 0.044715f * v * v * v);
  return 0.5f * v * (1.0f + tanhf(u));
}

// ---- transpose + f32->bf16 convert: in [E][R][C] f32 -> out [E][C][R] bf16 ----
__global__ __launch_bounds__(256) void k_transpose_cvt(
    const float* __restrict__ in, unsigned short* __restrict__ outp, int R, int C) {
  __shared__ float tile[32][33];
  int e = blockIdx.z;
  const float* inE = in + (size_t)e * R * C;
  unsigned short* outE = outp + (size_t)e * R * C;
  int c0 = blockIdx.x * 32, r0 = blockIdx.y * 32;
  int x = threadIdx.x, y = threadIdx.y;
#pragma unroll
  for (int i = 0; i < 32; i += 8)
    tile[y + i][x] = inE[(size_t)(r0 + y + i) * C + (c0 + x)];
  __syncthreads();
#pragma unroll
  for (int i = 0; i < 32; i += 8)
    outE[(size_t)(c0 + y + i) * R + (r0 + x)] = f2bf(tile[x][y + i]);
}

// ---- router: wave/token, f32 logits -> softmax -> top2; ALSO emits bf16 x ----
__global__ __launch_bounds__(256) void k_router(
    const float* __restrict__ x, const float* __restrict__ Wg,
    int* __restrict__ top_e, float* __restrict__ top_p,
    unsigned short* __restrict__ xbf) {
  int lane = threadIdx.x & 63;
  int t = blockIdx.x * 4 + (threadIdx.x >> 6);
  const float* xr = x + (size_t)t * DIM;
  int j0 = lane * 8;
  float4 xa = *(const float4*)(xr + j0);
  float4 xb = *(const float4*)(xr + j0 + 4);
  float xl[8] = {xa.x, xa.y, xa.z, xa.w, xb.x, xb.y, xb.z, xb.w};
  // bf16 copy of x (token order) -- replaces the scatter kernel's copy
  short8v pk;
#pragma unroll
  for (int i = 0; i < 8; ++i) pk[i] = (short)f2bf(xl[i]);
  *(short8v*)(xbf + (size_t)t * DIM + j0) = pk;

  float acc[8] = {0.f,0.f,0.f,0.f,0.f,0.f,0.f,0.f};
#pragma unroll
  for (int jj = 0; jj < 8; ++jj) {
    float4 w0 = *(const float4*)(Wg + (size_t)(j0 + jj) * NE);
    float4 w1 = *(const float4*)(Wg + (size_t)(j0 + jj) * NE + 4);
    acc[0] += xl[jj] * w0.x; acc[1] += xl[jj] * w0.y;
    acc[2] += xl[jj] * w0.z; acc[3] += xl[jj] * w0.w;
    acc[4] += xl[jj] * w1.x; acc[5] += xl[jj] * w1.y;
    acc[6] += xl[jj] * w1.z; acc[7] += xl[jj] * w1.w;
  }
#pragma unroll
  for (int off = 32; off >= 1; off >>= 1) {
#pragma unroll
    for (int e2 = 0; e2 < 8; ++e2) acc[e2] += __shfl_xor(acc[e2], off, 64);
  }
  if (lane == 0) {
    float m = acc[0];
#pragma unroll
    for (int e2 = 1; e2 < 8; ++e2) m = fmaxf(m, acc[e2]);
    float p[8]; float s = 0.f;
#pragma unroll
    for (int e2 = 0; e2 < 8; ++e2) { p[e2] = expf(acc[e2] - m); s += p[e2]; }
    float inv = 1.f / s;
    int i0 = 0;
#pragma unroll
    for (int e2 = 1; e2 < 8; ++e2) if (p[e2] > p[i0]) i0 = e2;
    int i1 = (i0 == 0) ? 1 : 0;
#pragma unroll
    for (int e2 = 0; e2 < 8; ++e2) if (e2 != i0 && p[e2] > p[i1]) i1 = e2;
    top_e[t * 2] = i0;  top_e[t * 2 + 1] = i1;
    top_p[t * 2] = p[i0] * inv;  top_p[t * 2 + 1] = p[i1] * inv;
  }
}

// ---- plan: deterministic local ranks via ballot, per-block expert counts ----
__global__ __launch_bounds__(256) void k_plan(
    const int* __restrict__ top_e, int* __restrict__ localRank,
    int* __restrict__ blockCounts) {
  __shared__ int cnt[4][NE];
  __shared__ int wbase[4][NE];
  int tid = threadIdx.x, lane = tid & 63, w = tid >> 6;
  int a = blockIdx.x * 256 + tid;
  int e = top_e[a];
  int rank = 0;
#pragma unroll
  for (int e2 = 0; e2 < NE; ++e2) {
    unsigned long long m = __ballot(e == e2);
    if (e == e2) rank = __popcll(m & ((1ULL << lane) - 1ULL));
    if (lane == 0) cnt[w][e2] = __popcll(m);
  }
  __syncthreads();
  if (tid < NE) {
    int s = 0;
#pragma unroll
    for (int w2 = 0; w2 < 4; ++w2) { wbase[w2][tid] = s; s += cnt[w2][tid]; }
    blockCounts[blockIdx.x * NE + tid] = s;
  }
  __syncthreads();
  localRank[a] = wbase[w][e] + rank;
}

// ---- scan: per-expert prefix over blocks, expert offsets, exact tile table --
__global__ void k_scan2(const int* __restrict__ blockCounts, int* __restrict__ baseBlk,
                        int* __restrict__ offs, int* __restrict__ tileE,
                        int* __restrict__ tileM0, int* __restrict__ nYTp, int nBlocks) {
  __shared__ int tot[NE];
  __shared__ int ytb[NE + 1];
  __shared__ int obase[NE];
  int tid = threadIdx.x;
  if (tid < NE) {
    int s = 0;
    for (int b = 0; b < nBlocks; ++b) { baseBlk[b * NE + tid] = s; s += blockCounts[b * NE + tid]; }
    tot[tid] = s;
  }
  __syncthreads();
  if (tid == 0) {
    int s = 0, yb = 0;
    for (int e = 0; e < NE; ++e) {
      offs[e] = s; obase[e] = s; ytb[e] = yb;
      yb += (tot[e] + 127) >> 7;
      s += tot[e];
    }
    offs[NE] = s; ytb[NE] = yb; nYTp[0] = yb;
  }
  __syncthreads();
  for (int e = 0; e < NE; ++e) {
    int nt = ytb[e + 1] - ytb[e];
    for (int i = tid; i < nt; i += 64) {
      tileE[ytb[e] + i]  = e;
      tileM0[ytb[e] + i] = obase[e] + i * 128;
    }
  }
}

// ---- posmap: pos -> (token, gate).  Replaces scatter (no x copy needed). ----
__global__ __launch_bounds__(256) void k_posmap(
    const int* __restrict__ top_e, const float* __restrict__ top_p,
    const int* __restrict__ localRank, const int* __restrict__ baseBlk,
    const int* __restrict__ offs, int* __restrict__ tok_of,
    float* __restrict__ gate_of) {
  int a = blockIdx.x * 256 + threadIdx.x;   // 0..16383
  int e = top_e[a];
  int pos = offs[e] + baseBlk[(a >> 8) * NE + e] + localRank[a];
  tok_of[pos] = a >> 1;
  gate_of[pos] = top_p[a];
}

// ============================================================================
// Persistent grouped NT GEMM, 128x128 tile, BK=64, 4 waves, single-buffer
// 32 KiB LDS, grid-stride over exact tile table, verified XOR swizzle
// (0 bank conflicts).  Inner loop IDENTICAL to round 5 (A/B attribution).
// EPI=0: A-rows gathered from xbf via tok_of; +bias, gelu, store bf16 H.
// EPI=1: A = Hb contiguous; +bias, gate-scale, atomicAdd into out[tok]
//        (exactly 2 f32 contributions per element -> commutative ->
//         bitwise-deterministic; out zeroed via memsetAsync).
// ============================================================================
#define MFMA1(d, a, b) d = __builtin_amdgcn_mfma_f32_16x16x32_bf16(a, b, d, 0, 0, 0)

template<int NX, int LOG2NX, int EPI>
__global__ __launch_bounds__(256, 4) void k_gemm_p(
    const unsigned short* __restrict__ A,   // EPI0: xbf [T][D]; EPI1: Hb [2T][H]
    const unsigned short* __restrict__ Bt,  // [E][N][K] bf16
    const float* __restrict__ bias,         // [E][N]
    const int* __restrict__ offs,           // [E+1]
    const int* __restrict__ tileE, const int* __restrict__ tileM0,
    const int* __restrict__ nYTp,
    const int* __restrict__ tok_of, const float* __restrict__ gate_of,
    unsigned short* __restrict__ Hout, float* __restrict__ outp, int K, int N) {
  __shared__ __align__(16) unsigned short Al[128 * 64];
  __shared__ __align__(16) unsigned short Bl[128 * 64];

  const int tid = threadIdx.x, lane = tid & 63, w = tid >> 6;
  const int wr = w >> 1, wc = w & 1;
  const int fr = lane & 15, fq = lane >> 4;
  const int sRow = tid >> 3;                                     // 0..31
  const int sCe = ((((tid & 7) << 4) ^ ((sRow & 7) << 4)) >> 1); // swz elem off
  const int NT = K >> 6;
  const int nWork = nYTp[0] << LOG2NX;

  for (int idx = blockIdx.x; idx < nWork; idx += gridDim.x) {
    const int yt = idx >> LOG2NX;
    const int xb = idx & (NX - 1);
    const int e = tileE[yt];
    const int m0 = tileM0[yt];
    const int rowEnd = offs[e + 1];
    const int n0 = xb * 128;
    const unsigned short* Be = Bt + (size_t)e * N * K;

    // per-tile A row indices (clamped); gather via tok_of for GEMM1
    int prow[4];
#pragma unroll
    for (int c_ = 0; c_ < 4; ++c_) {
      int ar_ = m0 + c_ * 32 + sRow; if (ar_ > rowEnd - 1) ar_ = rowEnd - 1;
      prow[c_] = (EPI == 0) ? tok_of[ar_] : ar_;
    }

    f32x4 acc[4][4];
#pragma unroll
    for (int m = 0; m < 4; ++m)
#pragma unroll
      for (int n = 0; n < 4; ++n) acc[m][n] = (f32x4){0.f, 0.f, 0.f, 0.f};

    for (int t = 0; t < NT; ++t) {
      // ---- stage tile t (A + B), pre-swizzled global source, linear dest ----
#pragma unroll
      for (int c_ = 0; c_ < 4; ++c_) {
        gload_lds16(A + (size_t)prow[c_] * K + (t << 6) + sCe,
                    (char*)&Al[0] + c_ * 4096 + (w << 10));
      }
#pragma unroll
      for (int c_ = 0; c_ < 4; ++c_) {
        int br_ = n0 + c_ * 32 + sRow;
        gload_lds16(Be + (size_t)br_ * K + (t << 6) + sCe,
                    (char*)&Bl[0] + c_ * 4096 + (w << 10));
      }
      __syncthreads();
      // ---- compute: 2x kk halves, swizzled ds_read_b128, 32 MFMA ----
#pragma unroll
      for (int kk = 0; kk < 2; ++kk) {
        short8v av[4], bv[4];
#pragma unroll
        for (int m = 0; m < 4; ++m) {
          int row_ = wr * 64 + m * 16 + fr;
          av[m] = *(const short8v*)((const char*)&Al[0] + row_ * 128 +
                    (((kk << 6) + (fq << 4)) ^ ((fr & 7) << 4)));
        }
#pragma unroll
        for (int n = 0; n < 4; ++n) {
          int row_ = wc * 64 + n * 16 + fr;
          bv[n] = *(const short8v*)((const char*)&Bl[0] + row_ * 128 +
                    (((kk << 6) + (fq << 4)) ^ ((fr & 7) << 4)));
        }
#pragma unroll
        for (int m = 0; m < 4; ++m)
#pragma unroll
          for (int n = 0; n < 4; ++n)
            MFMA1(acc[m][n], av[m], bv[n]);
      }
      __syncthreads();
    }

    // ---- epilogue ----
#pragma unroll
    for (int m = 0; m < 4; ++m) {
#pragma unroll
      for (int j = 0; j < 4; ++j) {
        int row = m0 + wr * 64 + m * 16 + fq * 4 + j;
        if (row >= rowEnd) continue;
        if (EPI == 0) {
#pragma unroll
          for (int n = 0; n < 4; ++n) {
            int col = n0 + wc * 64 + n * 16 + fr;
            float v = acc[m][n][j] + bias[(size_t)e * N + col];
            Hout[(size_t)row * N + col] = f2bf(gelu_f(v));
          }
        } else {
          int tok = tok_of[row];
          float g = gate_of[row];
          float* orow = outp + (size_t)tok * OUTD;
#pragma unroll
          for (int n = 0; n < 4; ++n) {
            int col = n0 + wc * 64 + n * 16 + fr;
            float v = acc[m][n][j] + bias[(size_t)e * N + col];
            atomicAdd(&orow[col], g * v);
          }
        }
      }
    }
  }
}

extern "C" void kernel_launch(void* const* d_in, const int* in_sizes, int n_in,
                              void* d_out, int out_size, void* d_ws, size_t ws_size,
                              hipStream_t stream) {
  const float* x  = (const float*)d_in[0];   // [T, D]
  const float* Wg = (const float*)d_in[1];   // [D, E]
  const float* W1 = (const float*)d_in[2];   // [E, D, H]
  const float* b1 = (const float*)d_in[3];   // [E, H]
  const float* W2 = (const float*)d_in[4];   // [E, H, O]
  const float* b2 = (const float*)d_in[5];   // [E, O]
  float* out = (float*)d_out;                // [T, O]

  char* p = (char*)d_ws;
  auto take = [&](size_t bytes) { char* r = p; p += (bytes + 255) & ~(size_t)255; return r; };
  unsigned short* W1t = (unsigned short*)take((size_t)NE * DIM * HID * 2);   // [E][H][D]
  unsigned short* W2t = (unsigned short*)take((size_t)NE * HID * OUTD * 2);  // [E][O][H]
  unsigned short* xbf = (unsigned short*)take((size_t)T_TOK * DIM * 2);      // [T][D]
  unsigned short* Hb  = (unsigned short*)take((size_t)2 * T_TOK * HID * 2);  // [2T][H]
  int* offs   = (int*)take(4096);
  int* tileE  = (int*)take(256 * 4);
  int* tileM0 = (int*)take(256 * 4);
  int* nYTp   = (int*)take(256);
  int*   top_e  = (int*)take((size_t)2 * T_TOK * 4);
  float* top_pv = (float*)take((size_t)2 * T_TOK * 4);
  int*   tok_of  = (int*)take((size_t)2 * T_TOK * 4);
  float* gate_of = (float*)take((size_t)2 * T_TOK * 4);
  int* localRank   = (int*)take((size_t)2 * T_TOK * 4);
  int* blockCounts = (int*)take((size_t)64 * NE * 4);
  int* baseBlk     = (int*)take((size_t)64 * NE * 4);

  const int PLAN_BLOCKS = (2 * T_TOK) / 256;   // 64

  hipMemsetAsync(out, 0, (size_t)T_TOK * OUTD * 4, stream);
  k_transpose_cvt<<<dim3(HID / 32, DIM / 32, NE), dim3(32, 8), 0, stream>>>(W1, W1t, DIM, HID);
  k_transpose_cvt<<<dim3(OUTD / 32, HID / 32, NE), dim3(32, 8), 0, stream>>>(W2, W2t, HID, OUTD);
  k_router<<<T_TOK / 4, 256, 0, stream>>>(x, Wg, top_e, top_pv, xbf);
  k_plan<<<PLAN_BLOCKS, 256, 0, stream>>>(top_e, localRank, blockCounts);
  k_scan2<<<1, 64, 0, stream>>>(blockCounts, baseBlk, offs, tileE, tileM0, nYTp, PLAN_BLOCKS);
  k_posmap<<<PLAN_BLOCKS, 256, 0, stream>>>(top_e, top_pv, localRank, baseBlk, offs, tok_of, gate_of);
  k_gemm_p<8, 3, 0><<<1024, 256, 0, stream>>>(xbf, W1t, b1, offs, tileE, tileM0, nYTp,
                                              tok_of, gate_of, Hb, nullptr, DIM, HID);
  k_gemm_p<4, 2, 1><<<512, 256, 0, stream>>>(Hb, W2t, b2, offs, tileE, tileM0, nYTp,
                                             tok_of, gate_of, nullptr, out, HID, OUTD);
}

// Round 7
// 153.533 us; speedup vs baseline: 1.3011x; 1.3011x over previous
//
#include <hip/hip_runtime.h>

#define T_TOK 8192
#define DIM   512
#define HID   1024
#define OUTD  512
#define NE    8

typedef __attribute__((ext_vector_type(8))) short short8v;   // 8 bf16 (4 VGPRs)
typedef __attribute__((ext_vector_type(4))) float f32x4;

__device__ __forceinline__ unsigned short f2bf(float f) {
  unsigned int u = __builtin_bit_cast(unsigned int, f);
  u += 0x7fffu + ((u >> 16) & 1u);            // RNE, finite inputs
  return (unsigned short)(u >> 16);
}

__device__ __forceinline__ void gload_lds16(const void* g, void* l) {
  __builtin_amdgcn_global_load_lds(
      (__attribute__((address_space(1))) void*)g,
      (__attribute__((address_space(3))) void*)l, 16, 0, 0);
}

__device__ __forceinline__ float gelu_f(float v) {
  const float c0 = 0.7978845608028654f;       // sqrt(2/pi), jax approximate=True
  float u = c0 * (v + 0.044715f * v * v * v);
  return 0.5f * v * (1.0f + tanhf(u));
}

// ---- transpose + f32->bf16 convert: in [E][R][C] f32 -> out [E][C][R] bf16 ----
__global__ __launch_bounds__(256) void k_transpose_cvt(
    const float* __restrict__ in, unsigned short* __restrict__ outp, int R, int C) {
  __shared__ float tile[32][33];
  int e = blockIdx.z;
  const float* inE = in + (size_t)e * R * C;
  unsigned short* outE = outp + (size_t)e * R * C;
  int c0 = blockIdx.x * 32, r0 = blockIdx.y * 32;
  int x = threadIdx.x, y = threadIdx.y;
#pragma unroll
  for (int i = 0; i < 32; i += 8)
    tile[y + i][x] = inE[(size_t)(r0 + y + i) * C + (c0 + x)];
  __syncthreads();
#pragma unroll
  for (int i = 0; i < 32; i += 8)
    outE[(size_t)(c0 + y + i) * R + (r0 + x)] = f2bf(tile[x][y + i]);
}

// ---- router: one wave per token, f32 logits -> softmax -> top2 (NO atomics) ----
__global__ __launch_bounds__(256) void k_router(
    const float* __restrict__ x, const float* __restrict__ Wg,
    int* __restrict__ top_e, float* __restrict__ top_p) {
  int lane = threadIdx.x & 63;
  int t = blockIdx.x * 4 + (threadIdx.x >> 6);
  const float* xr = x + (size_t)t * DIM;
  int j0 = lane * 8;
  float4 xa = *(const float4*)(xr + j0);
  float4 xb = *(const float4*)(xr + j0 + 4);
  float xl[8] = {xa.x, xa.y, xa.z, xa.w, xb.x, xb.y, xb.z, xb.w};
  float acc[8] = {0.f,0.f,0.f,0.f,0.f,0.f,0.f,0.f};
#pragma unroll
  for (int jj = 0; jj < 8; ++jj) {
    float4 w0 = *(const float4*)(Wg + (size_t)(j0 + jj) * NE);
    float4 w1 = *(const float4*)(Wg + (size_t)(j0 + jj) * NE + 4);
    acc[0] += xl[jj] * w0.x; acc[1] += xl[jj] * w0.y;
    acc[2] += xl[jj] * w0.z; acc[3] += xl[jj] * w0.w;
    acc[4] += xl[jj] * w1.x; acc[5] += xl[jj] * w1.y;
    acc[6] += xl[jj] * w1.z; acc[7] += xl[jj] * w1.w;
  }
#pragma unroll
  for (int off = 32; off >= 1; off >>= 1) {
#pragma unroll
    for (int e2 = 0; e2 < 8; ++e2) acc[e2] += __shfl_xor(acc[e2], off, 64);
  }
  if (lane == 0) {
    float m = acc[0];
#pragma unroll
    for (int e2 = 1; e2 < 8; ++e2) m = fmaxf(m, acc[e2]);
    float p[8]; float s = 0.f;
#pragma unroll
    for (int e2 = 0; e2 < 8; ++e2) { p[e2] = expf(acc[e2] - m); s += p[e2]; }
    float inv = 1.f / s;
    int i0 = 0;
#pragma unroll
    for (int e2 = 1; e2 < 8; ++e2) if (p[e2] > p[i0]) i0 = e2;
    int i1 = (i0 == 0) ? 1 : 0;
#pragma unroll
    for (int e2 = 0; e2 < 8; ++e2) if (e2 != i0 && p[e2] > p[i1]) i1 = e2;
    top_e[t * 2] = i0;  top_e[t * 2 + 1] = i1;
    top_p[t * 2] = p[i0] * inv;  top_p[t * 2 + 1] = p[i1] * inv;
  }
}

// ---- plan: deterministic local ranks via ballot, per-block expert counts ----
__global__ __launch_bounds__(256) void k_plan(
    const int* __restrict__ top_e, int* __restrict__ localRank,
    int* __restrict__ blockCounts) {
  __shared__ int cnt[4][NE];
  __shared__ int wbase[4][NE];
  int tid = threadIdx.x, lane = tid & 63, w = tid >> 6;
  int a = blockIdx.x * 256 + tid;
  int e = top_e[a];
  int rank = 0;
#pragma unroll
  for (int e2 = 0; e2 < NE; ++e2) {
    unsigned long long m = __ballot(e == e2);
    if (e == e2) rank = __popcll(m & ((1ULL << lane) - 1ULL));
    if (lane == 0) cnt[w][e2] = __popcll(m);
  }
  __syncthreads();
  if (tid < NE) {
    int s = 0;
#pragma unroll
    for (int w2 = 0; w2 < 4; ++w2) { wbase[w2][tid] = s; s += cnt[w2][tid]; }
    blockCounts[blockIdx.x * NE + tid] = s;
  }
  __syncthreads();
  localRank[a] = wbase[w][e] + rank;
}

// ---- scan: per-expert prefix over blocks + global expert offsets ----
__global__ void k_scan2(const int* __restrict__ blockCounts, int* __restrict__ baseBlk,
                        int* __restrict__ offs, int nBlocks) {
  __shared__ int tot[NE];
  int tid = threadIdx.x;
  if (tid < NE) {
    int s = 0;
    for (int b = 0; b < nBlocks; ++b) { baseBlk[b * NE + tid] = s; s += blockCounts[b * NE + tid]; }
    tot[tid] = s;
  }
  __syncthreads();
  if (tid == 0) {
    int s = 0;
    for (int e = 0; e < NE; ++e) { offs[e] = s; s += tot[e]; }
    offs[NE] = s;   // == 2*T_TOK
  }
}

// ---- scatter: pos = offs[e] + baseBlk[b][e] + localRank (NO atomics) ----
__global__ __launch_bounds__(256) void k_scatter(
    const float* __restrict__ x, const int* __restrict__ top_e,
    const int* __restrict__ localRank, const int* __restrict__ baseBlk,
    const int* __restrict__ offs, int* __restrict__ pos_of,
    unsigned short* __restrict__ Xp) {
  int lane = threadIdx.x & 63;
  int a = blockIdx.x * 4 + (threadIdx.x >> 6);   // 0..16383
  int t = a >> 1;
  int e = top_e[a];
  int pos = offs[e] + baseBlk[(a >> 8) * NE + e] + localRank[a];
  if (lane == 0) pos_of[a] = pos;
  const float* xr = x + (size_t)t * DIM + lane * 8;
  float4 xa = *(const float4*)xr;
  float4 xb = *(const float4*)(xr + 4);
  short8v pk;
  pk[0] = (short)f2bf(xa.x); pk[1] = (short)f2bf(xa.y);
  pk[2] = (short)f2bf(xa.z); pk[3] = (short)f2bf(xa.w);
  pk[4] = (short)f2bf(xb.x); pk[5] = (short)f2bf(xb.y);
  pk[6] = (short)f2bf(xb.z); pk[7] = (short)f2bf(xb.w);
  *(short8v*)(Xp + (size_t)pos * DIM + lane * 8) = pk;
}

// ============================================================================
// Expert->XCD pinned persistent grouped NT GEMM.  128x128 tile, BK=64,
// 4 waves, single-buffer 32 KiB LDS (4 blocks/CU), verified XOR swizzle
// (0 bank conflicts).  Inner loop IDENTICAL to round 5.
// Mapping: block b serves expert b%8 (== its XCD under round-robin dispatch);
// slot b/8 grid-strides the expert's (m-tile, n-tile) list, mt-major/n-minor
// so the NX n-tiles sharing an A m-tile are L2-co-resident.  Per-XCD traffic:
// A panel once + B panel once (round 4 measured FETCH 70->13.7 MB).
// ============================================================================
#define MFMA1(d, a, b) d = __builtin_amdgcn_mfma_f32_16x16x32_bf16(a, b, d, 0, 0, 0)

template<int NX, int LOG2NX, int EPI>
__global__ __launch_bounds__(256, 4) void k_gemm_x(
    const unsigned short* __restrict__ A,   // [2T][K] bf16 rows (expert-grouped)
    const unsigned short* __restrict__ Bt,  // [E][N][K] bf16
    const float* __restrict__ bias,         // [E][N]
    const int* __restrict__ offs,           // [E+1]
    unsigned short* __restrict__ Hout, float* __restrict__ Yout, int K, int N) {
  __shared__ __align__(16) unsigned short Al[128 * 64];
  __shared__ __align__(16) unsigned short Bl[128 * 64];

  const int e = blockIdx.x & 7;             // expert == XCD (round-robin)
  const int slot = blockIdx.x >> 3;
  const int nSlots = gridDim.x >> 3;
  const int rowBeg = offs[e], rowEnd = offs[e + 1];
  if (rowBeg >= rowEnd) return;
  const int nMT = (rowEnd - rowBeg + 127) >> 7;
  const int nWork = nMT << LOG2NX;
  const unsigned short* Be = Bt + (size_t)e * N * K;

  const int tid = threadIdx.x, lane = tid & 63, w = tid >> 6;
  const int wr = w >> 1, wc = w & 1;
  const int fr = lane & 15, fq = lane >> 4;
  const int sRow = tid >> 3;                                     // 0..31
  const int sCe = ((((tid & 7) << 4) ^ ((sRow & 7) << 4)) >> 1); // swz elem off
  const int NT = K >> 6;

  for (int idx = slot; idx < nWork; idx += nSlots) {
    const int mt = idx >> LOG2NX;
    const int xb = idx & (NX - 1);
    const int m0 = rowBeg + mt * 128;
    const int n0 = xb * 128;

    f32x4 acc[4][4];
#pragma unroll
    for (int m = 0; m < 4; ++m)
#pragma unroll
      for (int n = 0; n < 4; ++n) acc[m][n] = (f32x4){0.f, 0.f, 0.f, 0.f};

    for (int t = 0; t < NT; ++t) {
      // ---- stage tile t (A + B), pre-swizzled global source, linear dest ----
#pragma unroll
      for (int c_ = 0; c_ < 4; ++c_) {
        int ar_ = m0 + c_ * 32 + sRow; if (ar_ > rowEnd - 1) ar_ = rowEnd - 1;
        gload_lds16(A + (size_t)ar_ * K + (t << 6) + sCe,
                    (char*)&Al[0] + c_ * 4096 + (w << 10));
      }
#pragma unroll
      for (int c_ = 0; c_ < 4; ++c_) {
        int br_ = n0 + c_ * 32 + sRow;
        gload_lds16(Be + (size_t)br_ * K + (t << 6) + sCe,
                    (char*)&Bl[0] + c_ * 4096 + (w << 10));
      }
      __syncthreads();
      // ---- compute: 2x kk halves, swizzled ds_read_b128, 32 MFMA ----
#pragma unroll
      for (int kk = 0; kk < 2; ++kk) {
        short8v av[4], bv[4];
#pragma unroll
        for (int m = 0; m < 4; ++m) {
          int row_ = wr * 64 + m * 16 + fr;
          av[m] = *(const short8v*)((const char*)&Al[0] + row_ * 128 +
                    (((kk << 6) + (fq << 4)) ^ ((fr & 7) << 4)));
        }
#pragma unroll
        for (int n = 0; n < 4; ++n) {
          int row_ = wc * 64 + n * 16 + fr;
          bv[n] = *(const short8v*)((const char*)&Bl[0] + row_ * 128 +
                    (((kk << 6) + (fq << 4)) ^ ((fr & 7) << 4)));
        }
#pragma unroll
        for (int m = 0; m < 4; ++m)
#pragma unroll
          for (int n = 0; n < 4; ++n)
            MFMA1(acc[m][n], av[m], bv[n]);
      }
      __syncthreads();
    }

    // ---- epilogue ----
#pragma unroll
    for (int m = 0; m < 4; ++m) {
#pragma unroll
      for (int j = 0; j < 4; ++j) {
        int row = m0 + wr * 64 + m * 16 + fq * 4 + j;
        if (row >= rowEnd) continue;
#pragma unroll
        for (int n = 0; n < 4; ++n) {
          int col = n0 + wc * 64 + n * 16 + fr;
          float v = acc[m][n][j] + bias[(size_t)e * N + col];
          if (EPI == 0) Hout[(size_t)row * N + col] = f2bf(gelu_f(v));
          else          Yout[(size_t)row * N + col] = v;
        }
      }
    }
  }
}

// ---- combine: out[t] = g0*Y[p0] + g1*Y[p1] (deterministic, no atomics) ----
__global__ __launch_bounds__(256) void k_combine(
    const float* __restrict__ Y, const int* __restrict__ pos_of,
    const float* __restrict__ top_p, float* __restrict__ out) {
  int lane = threadIdx.x & 63;
  int t = blockIdx.x * 4 + (threadIdx.x >> 6);
  int p0 = pos_of[t * 2], p1 = pos_of[t * 2 + 1];
  float g0 = top_p[t * 2], g1 = top_p[t * 2 + 1];
  const float4* y0 = (const float4*)(Y + (size_t)p0 * OUTD + lane * 8);
  const float4* y1 = (const float4*)(Y + (size_t)p1 * OUTD + lane * 8);
  float4* o = (float4*)(out + (size_t)t * OUTD + lane * 8);
  float4 a0 = y0[0], a1 = y0[1], c0 = y1[0], c1 = y1[1];
  float4 r0, r1;
  r0.x = g0 * a0.x + g1 * c0.x; r0.y = g0 * a0.y + g1 * c0.y;
  r0.z = g0 * a0.z + g1 * c0.z; r0.w = g0 * a0.w + g1 * c0.w;
  r1.x = g0 * a1.x + g1 * c1.x; r1.y = g0 * a1.y + g1 * c1.y;
  r1.z = g0 * a1.z + g1 * c1.z; r1.w = g0 * a1.w + g1 * c1.w;
  o[0] = r0; o[1] = r1;
}

extern "C" void kernel_launch(void* const* d_in, const int* in_sizes, int n_in,
                              void* d_out, int out_size, void* d_ws, size_t ws_size,
                              hipStream_t stream) {
  const float* x  = (const float*)d_in[0];   // [T, D]
  const float* Wg = (const float*)d_in[1];   // [D, E]
  const float* W1 = (const float*)d_in[2];   // [E, D, H]
  const float* b1 = (const float*)d_in[3];   // [E, H]
  const float* W2 = (const float*)d_in[4];   // [E, H, O]
  const float* b2 = (const float*)d_in[5];   // [E, O]
  float* out = (float*)d_out;                // [T, O]

  char* p = (char*)d_ws;
  auto take = [&](size_t bytes) { char* r = p; p += (bytes + 255) & ~(size_t)255; return r; };
  unsigned short* W1t = (unsigned short*)take((size_t)NE * DIM * HID * 2);   // [E][H][D]
  unsigned short* W2t = (unsigned short*)take((size_t)NE * HID * OUTD * 2);  // [E][O][H]
  unsigned short* Xp  = (unsigned short*)take((size_t)2 * T_TOK * DIM * 2);  // [2T][D]
  unsigned short* Hb  = (unsigned short*)take((size_t)2 * T_TOK * HID * 2);  // [2T][H]
  float*          Yb  = (float*)take((size_t)2 * T_TOK * OUTD * 4);          // [2T][O]
  int* offs   = (int*)take(4096);
  int*   top_e  = (int*)take((size_t)2 * T_TOK * 4);
  float* top_pv = (float*)take((size_t)2 * T_TOK * 4);
  int*   pos_of = (int*)take((size_t)2 * T_TOK * 4);
  int* localRank   = (int*)take((size_t)2 * T_TOK * 4);
  int* blockCounts = (int*)take((size_t)64 * NE * 4);
  int* baseBlk     = (int*)take((size_t)64 * NE * 4);

  const int PLAN_BLOCKS = (2 * T_TOK) / 256;   // 64

  k_transpose_cvt<<<dim3(HID / 32, DIM / 32, NE), dim3(32, 8), 0, stream>>>(W1, W1t, DIM, HID);
  k_transpose_cvt<<<dim3(OUTD / 32, HID / 32, NE), dim3(32, 8), 0, stream>>>(W2, W2t, HID, OUTD);
  k_router<<<T_TOK / 4, 256, 0, stream>>>(x, Wg, top_e, top_pv);
  k_plan<<<PLAN_BLOCKS, 256, 0, stream>>>(top_e, localRank, blockCounts);
  k_scan2<<<1, 64, 0, stream>>>(blockCounts, baseBlk, offs, PLAN_BLOCKS);
  k_scatter<<<(2 * T_TOK) / 4, 256, 0, stream>>>(x, top_e, localRank, baseBlk, offs, pos_of, Xp);
  k_gemm_x<8, 3, 0><<<1024, 256, 0, stream>>>(Xp, W1t, b1, offs, Hb, nullptr, DIM, HID);
  k_gemm_x<4, 2, 1><<<512, 256, 0, stream>>>(Hb, W2t, b2, offs, nullptr, Yb, HID, OUTD);
  k_combine<<<T_TOK / 4, 256, 0, stream>>>(Yb, pos_of, top_pv, out);
}

// Round 8
// 132.806 us; speedup vs baseline: 1.5042x; 1.1561x over previous
//
#include <hip/hip_runtime.h>

#define T_TOK 8192
#define DIM   512
#define HID   1024
#define OUTD  512
#define NE    8

typedef __attribute__((ext_vector_type(8))) short short8v;   // 8 bf16 (4 VGPRs)
typedef __attribute__((ext_vector_type(4))) float f32x4;

__device__ __forceinline__ unsigned short f2bf(float f) {
  unsigned int u = __builtin_bit_cast(unsigned int, f);
  u += 0x7fffu + ((u >> 16) & 1u);            // RNE, finite inputs
  return (unsigned short)(u >> 16);
}

__device__ __forceinline__ float bf2f(unsigned short h) {
  unsigned int u = ((unsigned int)h) << 16;
  return __builtin_bit_cast(float, u);
}

__device__ __forceinline__ void gload_lds16(const void* g, void* l) {
  __builtin_amdgcn_global_load_lds(
      (__attribute__((address_space(1))) void*)g,
      (__attribute__((address_space(3))) void*)l, 16, 0, 0);
}

// gelu tanh-approx, exact identity: 0.5v(1+tanh(u)) = v * sigmoid(2u)
__device__ __forceinline__ float gelu_f(float v) {
  const float c0 = 0.7978845608028654f;       // sqrt(2/pi), jax approximate=True
  float u = c0 * (v + 0.044715f * v * v * v);
  return v / (1.0f + __expf(-2.0f * u));
}

// ---- merged transpose+cvt for W1 and W2: [E][R][C] f32 -> [E][C][R] bf16 ----
__global__ __launch_bounds__(256) void k_trans_all(
    const float* __restrict__ W1, const float* __restrict__ W2,
    unsigned short* __restrict__ W1t, unsigned short* __restrict__ W2t) {
  __shared__ float tile[32][33];
  int bid = blockIdx.x;
  int which = bid >> 12;            // 0: W1 (512x1024), 1: W2 (1024x512)
  int r = bid & 4095;
  int e = r >> 9;
  int t = r & 511;
  int R = which ? HID : DIM;
  int C = which ? OUTD : HID;
  int tx, ty;
  if (which == 0) { ty = t >> 5; tx = t & 31; }   // 16 x 32 tiles
  else            { ty = t >> 4; tx = t & 15; }   // 32 x 16 tiles
  const float* inE = (which ? W2 : W1) + (size_t)e * R * C;
  unsigned short* outE = (which ? W2t : W1t) + (size_t)e * R * C;
  int c0 = tx * 32, r0 = ty * 32;
  int x = threadIdx.x, y = threadIdx.y;
#pragma unroll
  for (int i = 0; i < 32; i += 8)
    tile[y + i][x] = inE[(size_t)(r0 + y + i) * C + (c0 + x)];
  __syncthreads();
#pragma unroll
  for (int i = 0; i < 32; i += 8)
    outE[(size_t)(c0 + y + i) * R + (r0 + x)] = f2bf(tile[x][y + i]);
}

// ---- router: one wave per token, f32 logits -> softmax -> top2 (NO atomics) ----
__global__ __launch_bounds__(256) void k_router(
    const float* __restrict__ x, const float* __restrict__ Wg,
    int* __restrict__ top_e, float* __restrict__ top_p) {
  int lane = threadIdx.x & 63;
  int t = blockIdx.x * 4 + (threadIdx.x >> 6);
  const float* xr = x + (size_t)t * DIM;
  int j0 = lane * 8;
  float4 xa = *(const float4*)(xr + j0);
  float4 xb = *(const float4*)(xr + j0 + 4);
  float xl[8] = {xa.x, xa.y, xa.z, xa.w, xb.x, xb.y, xb.z, xb.w};
  float acc[8] = {0.f,0.f,0.f,0.f,0.f,0.f,0.f,0.f};
#pragma unroll
  for (int jj = 0; jj < 8; ++jj) {
    float4 w0 = *(const float4*)(Wg + (size_t)(j0 + jj) * NE);
    float4 w1 = *(const float4*)(Wg + (size_t)(j0 + jj) * NE + 4);
    acc[0] += xl[jj] * w0.x; acc[1] += xl[jj] * w0.y;
    acc[2] += xl[jj] * w0.z; acc[3] += xl[jj] * w0.w;
    acc[4] += xl[jj] * w1.x; acc[5] += xl[jj] * w1.y;
    acc[6] += xl[jj] * w1.z; acc[7] += xl[jj] * w1.w;
  }
#pragma unroll
  for (int off = 32; off >= 1; off >>= 1) {
#pragma unroll
    for (int e2 = 0; e2 < 8; ++e2) acc[e2] += __shfl_xor(acc[e2], off, 64);
  }
  if (lane == 0) {
    float m = acc[0];
#pragma unroll
    for (int e2 = 1; e2 < 8; ++e2) m = fmaxf(m, acc[e2]);
    float p[8]; float s = 0.f;
#pragma unroll
    for (int e2 = 0; e2 < 8; ++e2) { p[e2] = expf(acc[e2] - m); s += p[e2]; }
    float inv = 1.f / s;
    int i0 = 0;
#pragma unroll
    for (int e2 = 1; e2 < 8; ++e2) if (p[e2] > p[i0]) i0 = e2;
    int i1 = (i0 == 0) ? 1 : 0;
#pragma unroll
    for (int e2 = 0; e2 < 8; ++e2) if (e2 != i0 && p[e2] > p[i1]) i1 = e2;
    top_e[t * 2] = i0;  top_e[t * 2 + 1] = i1;
    top_p[t * 2] = p[i0] * inv;  top_p[t * 2 + 1] = p[i1] * inv;
  }
}

// ---- plan: deterministic local ranks via ballot, per-block expert counts ----
__global__ __launch_bounds__(256) void k_plan(
    const int* __restrict__ top_e, int* __restrict__ localRank,
    int* __restrict__ blockCounts) {
  __shared__ int cnt[4][NE];
  __shared__ int wbase[4][NE];
  int tid = threadIdx.x, lane = tid & 63, w = tid >> 6;
  int a = blockIdx.x * 256 + tid;
  int e = top_e[a];
  int rank = 0;
#pragma unroll
  for (int e2 = 0; e2 < NE; ++e2) {
    unsigned long long m = __ballot(e == e2);
    if (e == e2) rank = __popcll(m & ((1ULL << lane) - 1ULL));
    if (lane == 0) cnt[w][e2] = __popcll(m);
  }
  __syncthreads();
  if (tid < NE) {
    int s = 0;
#pragma unroll
    for (int w2 = 0; w2 < 4; ++w2) { wbase[w2][tid] = s; s += cnt[w2][tid]; }
    blockCounts[blockIdx.x * NE + tid] = s;
  }
  __syncthreads();
  localRank[a] = wbase[w][e] + rank;
}

// ---- scan: per-expert prefix over blocks + global expert offsets ----
__global__ void k_scan2(const int* __restrict__ blockCounts, int* __restrict__ baseBlk,
                        int* __restrict__ offs, int nBlocks) {
  __shared__ int tot[NE];
  int tid = threadIdx.x;
  if (tid < NE) {
    int s = 0;
    for (int b = 0; b < nBlocks; ++b) { baseBlk[b * NE + tid] = s; s += blockCounts[b * NE + tid]; }
    tot[tid] = s;
  }
  __syncthreads();
  if (tid == 0) {
    int s = 0;
    for (int e = 0; e < NE; ++e) { offs[e] = s; s += tot[e]; }
    offs[NE] = s;   // == 2*T_TOK
  }
}

// ---- scatter: pos = offs[e] + baseBlk[b][e] + localRank (NO atomics) ----
__global__ __launch_bounds__(256) void k_scatter(
    const float* __restrict__ x, const int* __restrict__ top_e,
    const int* __restrict__ localRank, const int* __restrict__ baseBlk,
    const int* __restrict__ offs, int* __restrict__ pos_of,
    unsigned short* __restrict__ Xp) {
  int lane = threadIdx.x & 63;
  int a = blockIdx.x * 4 + (threadIdx.x >> 6);   // 0..16383
  int t = a >> 1;
  int e = top_e[a];
  int pos = offs[e] + baseBlk[(a >> 8) * NE + e] + localRank[a];
  if (lane == 0) pos_of[a] = pos;
  const float* xr = x + (size_t)t * DIM + lane * 8;
  float4 xa = *(const float4*)xr;
  float4 xb = *(const float4*)(xr + 4);
  short8v pk;
  pk[0] = (short)f2bf(xa.x); pk[1] = (short)f2bf(xa.y);
  pk[2] = (short)f2bf(xa.z); pk[3] = (short)f2bf(xa.w);
  pk[4] = (short)f2bf(xb.x); pk[5] = (short)f2bf(xb.y);
  pk[6] = (short)f2bf(xb.z); pk[7] = (short)f2bf(xb.w);
  *(short8v*)(Xp + (size_t)pos * DIM + lane * 8) = pk;
}

// ============================================================================
// Expert->XCD pinned persistent grouped NT GEMM (round-7 structure, verified:
// FETCH 70->15 MB, 0 bank conflicts).  128x128 tile, BK=64, 4 waves,
// single-buffer 32 KiB LDS, 4 blocks/CU.  CHANGES THIS ROUND:
//  - stage base addresses hoisted out of the K-loop (uniform +t*128B offset)
//  - EPI=1 stores bf16 (gate applied later in combine)
//  - cheap-exact gelu in EPI=0
// ============================================================================
#define MFMA1(d, a, b) d = __builtin_amdgcn_mfma_f32_16x16x32_bf16(a, b, d, 0, 0, 0)

template<int NX, int LOG2NX, int EPI>
__global__ __launch_bounds__(256, 4) void k_gemm_x(
    const unsigned short* __restrict__ A,   // [2T][K] bf16 rows (expert-grouped)
    const unsigned short* __restrict__ Bt,  // [E][N][K] bf16
    const float* __restrict__ bias,         // [E][N]
    const int* __restrict__ offs,           // [E+1]
    unsigned short* __restrict__ Hout, unsigned short* __restrict__ Ybf,
    int K, int N) {
  __shared__ __align__(16) unsigned short Al[128 * 64];
  __shared__ __align__(16) unsigned short Bl[128 * 64];

  const int e = blockIdx.x & 7;             // expert == XCD (round-robin)
  const int slot = blockIdx.x >> 3;
  const int nSlots = gridDim.x >> 3;
  const int rowBeg = offs[e], rowEnd = offs[e + 1];
  if (rowBeg >= rowEnd) return;
  const int nMT = (rowEnd - rowBeg + 127) >> 7;
  const int nWork = nMT << LOG2NX;
  const unsigned short* Be = Bt + (size_t)e * N * K;

  const int tid = threadIdx.x, lane = tid & 63, w = tid >> 6;
  const int wr = w >> 1, wc = w & 1;
  const int fr = lane & 15, fq = lane >> 4;
  const int sRow = tid >> 3;                                     // 0..31
  const int sCe = ((((tid & 7) << 4) ^ ((sRow & 7) << 4)) >> 1); // swz elem off
  const int NT = K >> 6;

  for (int idx = slot; idx < nWork; idx += nSlots) {
    const int mt = idx >> LOG2NX;
    const int xb = idx & (NX - 1);
    const int m0 = rowBeg + mt * 128;
    const int n0 = xb * 128;

    // hoisted stage base addresses (byte pointers incl. swizzled elem offset)
    const char* aP[4]; const char* bP[4];
#pragma unroll
    for (int c_ = 0; c_ < 4; ++c_) {
      int ar_ = m0 + c_ * 32 + sRow; if (ar_ > rowEnd - 1) ar_ = rowEnd - 1;
      aP[c_] = (const char*)(A + (size_t)ar_ * K + sCe);
      int br_ = n0 + c_ * 32 + sRow;
      bP[c_] = (const char*)(Be + (size_t)br_ * K + sCe);
    }

    f32x4 acc[4][4];
#pragma unroll
    for (int m = 0; m < 4; ++m)
#pragma unroll
      for (int n = 0; n < 4; ++n) acc[m][n] = (f32x4){0.f, 0.f, 0.f, 0.f};

    for (int t = 0; t < NT; ++t) {
      const int tOff = t << 7;                 // +128 B per K-step
      // ---- stage tile t (A + B), pre-swizzled global source, linear dest ----
#pragma unroll
      for (int c_ = 0; c_ < 4; ++c_)
        gload_lds16(aP[c_] + tOff, (char*)&Al[0] + c_ * 4096 + (w << 10));
#pragma unroll
      for (int c_ = 0; c_ < 4; ++c_)
        gload_lds16(bP[c_] + tOff, (char*)&Bl[0] + c_ * 4096 + (w << 10));
      __syncthreads();
      // ---- compute: 2x kk halves, swizzled ds_read_b128, 32 MFMA ----
#pragma unroll
      for (int kk = 0; kk < 2; ++kk) {
        short8v av[4], bv[4];
#pragma unroll
        for (int m = 0; m < 4; ++m) {
          int row_ = wr * 64 + m * 16 + fr;
          av[m] = *(const short8v*)((const char*)&Al[0] + row_ * 128 +
                    (((kk << 6) + (fq << 4)) ^ ((fr & 7) << 4)));
        }
#pragma unroll
        for (int n = 0; n < 4; ++n) {
          int row_ = wc * 64 + n * 16 + fr;
          bv[n] = *(const short8v*)((const char*)&Bl[0] + row_ * 128 +
                    (((kk << 6) + (fq << 4)) ^ ((fr & 7) << 4)));
        }
#pragma unroll
        for (int m = 0; m < 4; ++m)
#pragma unroll
          for (int n = 0; n < 4; ++n)
            MFMA1(acc[m][n], av[m], bv[n]);
      }
      __syncthreads();
    }

    // ---- epilogue ----
#pragma unroll
    for (int m = 0; m < 4; ++m) {
#pragma unroll
      for (int j = 0; j < 4; ++j) {
        int row = m0 + wr * 64 + m * 16 + fq * 4 + j;
        if (row >= rowEnd) continue;
#pragma unroll
        for (int n = 0; n < 4; ++n) {
          int col = n0 + wc * 64 + n * 16 + fr;
          float v = acc[m][n][j] + bias[(size_t)e * N + col];
          if (EPI == 0) Hout[(size_t)row * N + col] = f2bf(gelu_f(v));
          else          Ybf[(size_t)row * N + col] = f2bf(v);
        }
      }
    }
  }
}

// ---- combine: out[t] = g0*Y[p0] + g1*Y[p1] (bf16 reads, f32 math/store) ----
__global__ __launch_bounds__(256) void k_combine(
    const unsigned short* __restrict__ Y, const int* __restrict__ pos_of,
    const float* __restrict__ top_p, float* __restrict__ out) {
  int lane = threadIdx.x & 63;
  int t = blockIdx.x * 4 + (threadIdx.x >> 6);
  int p0 = pos_of[t * 2], p1 = pos_of[t * 2 + 1];
  float g0 = top_p[t * 2], g1 = top_p[t * 2 + 1];
  short8v ya = *(const short8v*)(Y + (size_t)p0 * OUTD + lane * 8);
  short8v yb = *(const short8v*)(Y + (size_t)p1 * OUTD + lane * 8);
  float4 r0, r1;
  r0.x = g0 * bf2f((unsigned short)ya[0]) + g1 * bf2f((unsigned short)yb[0]);
  r0.y = g0 * bf2f((unsigned short)ya[1]) + g1 * bf2f((unsigned short)yb[1]);
  r0.z = g0 * bf2f((unsigned short)ya[2]) + g1 * bf2f((unsigned short)yb[2]);
  r0.w = g0 * bf2f((unsigned short)ya[3]) + g1 * bf2f((unsigned short)yb[3]);
  r1.x = g0 * bf2f((unsigned short)ya[4]) + g1 * bf2f((unsigned short)yb[4]);
  r1.y = g0 * bf2f((unsigned short)ya[5]) + g1 * bf2f((unsigned short)yb[5]);
  r1.z = g0 * bf2f((unsigned short)ya[6]) + g1 * bf2f((unsigned short)yb[6]);
  r1.w = g0 * bf2f((unsigned short)ya[7]) + g1 * bf2f((unsigned short)yb[7]);
  float4* o = (float4*)(out + (size_t)t * OUTD + lane * 8);
  o[0] = r0; o[1] = r1;
}

extern "C" void kernel_launch(void* const* d_in, const int* in_sizes, int n_in,
                              void* d_out, int out_size, void* d_ws, size_t ws_size,
                              hipStream_t stream) {
  const float* x  = (const float*)d_in[0];   // [T, D]
  const float* Wg = (const float*)d_in[1];   // [D, E]
  const float* W1 = (const float*)d_in[2];   // [E, D, H]
  const float* b1 = (const float*)d_in[3];   // [E, H]
  const float* W2 = (const float*)d_in[4];   // [E, H, O]
  const float* b2 = (const float*)d_in[5];   // [E, O]
  float* out = (float*)d_out;                // [T, O]

  char* p = (char*)d_ws;
  auto take = [&](size_t bytes) { char* r = p; p += (bytes + 255) & ~(size_t)255; return r; };
  unsigned short* W1t = (unsigned short*)take((size_t)NE * DIM * HID * 2);   // [E][H][D]
  unsigned short* W2t = (unsigned short*)take((size_t)NE * HID * OUTD * 2);  // [E][O][H]
  unsigned short* Xp  = (unsigned short*)take((size_t)2 * T_TOK * DIM * 2);  // [2T][D]
  unsigned short* Hb  = (unsigned short*)take((size_t)2 * T_TOK * HID * 2);  // [2T][H]
  unsigned short* Yb  = (unsigned short*)take((size_t)2 * T_TOK * OUTD * 2); // [2T][O] bf16
  int* offs   = (int*)take(4096);
  int*   top_e  = (int*)take((size_t)2 * T_TOK * 4);
  float* top_pv = (float*)take((size_t)2 * T_TOK * 4);
  int*   pos_of = (int*)take((size_t)2 * T_TOK * 4);
  int* localRank   = (int*)take((size_t)2 * T_TOK * 4);
  int* blockCounts = (int*)take((size_t)64 * NE * 4);
  int* baseBlk     = (int*)take((size_t)64 * NE * 4);

  const int PLAN_BLOCKS = (2 * T_TOK) / 256;   // 64

  k_trans_all<<<8192, dim3(32, 8), 0, stream>>>(W1, W2, W1t, W2t);
  k_router<<<T_TOK / 4, 256, 0, stream>>>(x, Wg, top_e, top_pv);
  k_plan<<<PLAN_BLOCKS, 256, 0, stream>>>(top_e, localRank, blockCounts);
  k_scan2<<<1, 64, 0, stream>>>(blockCounts, baseBlk, offs, PLAN_BLOCKS);
  k_scatter<<<(2 * T_TOK) / 4, 256, 0, stream>>>(x, top_e, localRank, baseBlk, offs, pos_of, Xp);
  k_gemm_x<8, 3, 0><<<1024, 256, 0, stream>>>(Xp, W1t, b1, offs, Hb, nullptr, DIM, HID);
  k_gemm_x<4, 2, 1><<<512, 256, 0, stream>>>(Hb, W2t, b2, offs, nullptr, Yb, HID, OUTD);
  k_combine<<<T_TOK / 4, 256, 0, stream>>>(Yb, pos_of, top_pv, out);
}